// Round 6
// baseline (162.807 us; speedup 1.0000x reference)
//
#include <hip/hip_runtime.h>
#include <hip/hip_bf16.h>
#include <math.h>

#define S 4096
#define CIN 256
#define C3 768
#define NH 8
#define HD 32
#define KSPLIT 4

static constexpr float EPS = 1e-4f;

typedef __attribute__((ext_vector_type(8))) __bf16 bf16x8;
typedef __attribute__((ext_vector_type(4))) float f32x4;
typedef __attribute__((ext_vector_type(16))) float f32x16;
typedef __attribute__((ext_vector_type(8))) unsigned short u16x8;
typedef __attribute__((ext_vector_type(4))) unsigned u32x4;

static inline __device__ ushort f2bf(float f) {  // RN-even
  unsigned u = __float_as_uint(f);
  return (ushort)((u + 0x7fffu + ((u >> 16) & 1u)) >> 16);
}

// v_cvt_pk_bf16_f32: dst.lo16 = bf16(lo), dst.hi16 = bf16(hi); RNE (no builtin)
static inline __device__ unsigned cvt_pk_bf16(float lo, float hi) {
  unsigned r;
  asm("v_cvt_pk_bf16_f32 %0, %1, %2" : "=v"(r) : "v"(lo), "v"(hi));
  return r;
}
// v_permlane32_swap_b32: a.hi32lanes <-> b.lo32lanes.
static inline __device__ void plane32_swap(unsigned& a, unsigned& b) {
  asm("v_permlane32_swap_b32 %0, %1" : "+v"(a), "+v"(b));
}

#define EXP2 __builtin_amdgcn_exp2f

// Convert one 32x32 QK score tile (D-layout: col=q=lane&31, row=k=(r&3)+8*(r>>2)+4*hi)
// to two PV operand fragments (col/row=q, k = frag*8 elements at 8*hi+j) fully
// in registers: 8 cvt_pk + 4 permlane32_swap. plo covers k 0..15, phi 16..31.
static inline __device__ void s_to_pf(const f32x16 s, bf16x8& plo, bf16x8& phi) {
  unsigned c0 = cvt_pk_bf16(EXP2(s[0]), EXP2(s[1]));    // hi0:k(0,1)   hi1:k(4,5)
  unsigned c1 = cvt_pk_bf16(EXP2(s[2]), EXP2(s[3]));    // hi0:k(2,3)   hi1:k(6,7)
  unsigned c2 = cvt_pk_bf16(EXP2(s[4]), EXP2(s[5]));    // hi0:k(8,9)   hi1:k(12,13)
  unsigned c3 = cvt_pk_bf16(EXP2(s[6]), EXP2(s[7]));    // hi0:k(10,11) hi1:k(14,15)
  plane32_swap(c0, c2);
  plane32_swap(c1, c3);
  u32x4 lo4 = {c0, c1, c2, c3};
  plo = __builtin_bit_cast(bf16x8, lo4);
  unsigned c4 = cvt_pk_bf16(EXP2(s[8]), EXP2(s[9]));
  unsigned c5 = cvt_pk_bf16(EXP2(s[10]), EXP2(s[11]));
  unsigned c6 = cvt_pk_bf16(EXP2(s[12]), EXP2(s[13]));
  unsigned c7 = cvt_pk_bf16(EXP2(s[14]), EXP2(s[15]));
  plane32_swap(c4, c6);
  plane32_swap(c5, c7);
  u32x4 hi4 = {c4, c5, c6, c7};
  phi = __builtin_bit_cast(bf16x8, hi4);
}

// ---------------- weight norm (both weights, one launch) ---------------------
__global__ __launch_bounds__(256) void wnorm_kernel(const float* __restrict__ w_qkv,
                                                    const float* __restrict__ w_out,
                                                    ushort* __restrict__ wqb,
                                                    ushort* __restrict__ wob) {
  const int row = blockIdx.x * 4 + (threadIdx.x >> 6);
  const int lane = threadIdx.x & 63;
  const bool is_q = row < C3;
  const float* wr = (is_q ? w_qkv + (size_t)row * CIN : w_out + (size_t)(row - C3) * CIN);
  float v0 = wr[lane], v1 = wr[lane + 64], v2 = wr[lane + 128], v3 = wr[lane + 192];
  float ss = v0 * v0 + v1 * v1 + v2 * v2 + v3 * v3;
  #pragma unroll
  for (int off = 32; off > 0; off >>= 1) ss += __shfl_down(ss, off, 64);
  ss = __shfl(ss, 0, 64);
  const float scale = 1.0f / (sqrtf(ss) + 16.0f * EPS);
  ushort* whr = (is_q ? wqb + (size_t)row * CIN : wob + (size_t)(row - C3) * CIN);
  whr[lane] = f2bf(v0 * scale);
  whr[lane + 64] = f2bf(v1 * scale);
  whr[lane + 128] = f2bf(v2 * scale);
  whr[lane + 192] = f2bf(v3 * scale);
}

// ---------------- X [b][c][s] fp32 -> Xt [b][s][c] bf16 ----------------------
__global__ __launch_bounds__(256) void xt_kernel(const float* __restrict__ X,
                                                 ushort* __restrict__ Xt) {
  const int b = blockIdx.z;
  const int s0 = blockIdx.x * 64, c0 = blockIdx.y * 64;
  __shared__ ushort T[64][72];
  const int tc = threadIdx.x >> 4;
  const int ts = threadIdx.x & 15;
  #pragma unroll
  for (int i = 0; i < 4; i++) {
    const float4 v = *(const float4*)&X[((size_t)(b * CIN + c0 + tc + 16 * i)) * S + s0 + ts * 4];
    ushort4 u;
    u.x = f2bf(v.x); u.y = f2bf(v.y); u.z = f2bf(v.z); u.w = f2bf(v.w);
    *(ushort4*)&T[tc + 16 * i][ts * 4] = u;
  }
  __syncthreads();
  #pragma unroll
  for (int i = 0; i < 4; i++) {
    const int sr = tc + 16 * i;
    ushort4 u;
    u.x = T[ts * 4 + 0][sr];
    u.y = T[ts * 4 + 1][sr];
    u.z = T[ts * 4 + 2][sr];
    u.w = T[ts * 4 + 3][sr];
    *(ushort4*)&Xt[((size_t)b * S + s0 + sr) * CIN + c0 + ts * 4] = u;
  }
}

// ---------------- conv1 fused with pixel-norm + layout fan-out ---------------
// Q written as [bh][q][HD] rows (loaded once per attn wave). K and V written in
// MFMA-FRAGMENT-ORDERED PANELS so every attn fragment load is base + lane*16B
// (dense 1KB/instruction, 8 cache lines instead of 32-64):
//   Kpan: [bh][key>>5][half][key&31][hi][8]  (half = ch/16, hi = (ch&15)>>3)
//   Vpan: [bh][key>>6][kc][d][hi][8]         (kc = (key&63)>>4, hi = (key&15)>>3)
__global__ __launch_bounds__(256) void conv1_fused_kernel(const ushort* __restrict__ W,
                                                          const ushort* __restrict__ Bm,
                                                          ushort* __restrict__ Qn,
                                                          ushort* __restrict__ Kn,
                                                          ushort* __restrict__ Vt) {
  const int b = blockIdx.z;
  const int wid = threadIdx.x >> 6, lane = threadIdx.x & 63;
  const int col = lane & 15, quad = lane >> 4;
  const int m0 = blockIdx.y * 64 + (wid >> 1) * 32;  // 32-aligned: one head group
  const int n0 = blockIdx.x * 128 + (wid & 1) * 64;
  const ushort* Bb = Bm + (size_t)b * S * CIN;
  f32x4 acc[2][4] = {};
  #pragma unroll
  for (int k0 = 0; k0 < CIN; k0 += 32) {
    bf16x8 af[2], bf[4];
    #pragma unroll
    for (int mi = 0; mi < 2; mi++)
      af[mi] = *(const bf16x8*)&W[(size_t)(m0 + mi * 16 + col) * CIN + k0 + quad * 8];
    #pragma unroll
    for (int ni = 0; ni < 4; ni++)
      bf[ni] = *(const bf16x8*)&Bb[(size_t)(n0 + ni * 16 + col) * CIN + k0 + quad * 8];
    #pragma unroll
    for (int mi = 0; mi < 2; mi++)
      #pragma unroll
      for (int ni = 0; ni < 4; ni++)
        acc[mi][ni] = __builtin_amdgcn_mfma_f32_16x16x32_bf16(af[mi], bf[ni], acc[mi][ni], 0, 0, 0);
  }

  const int g = m0 >> 5;   // 0..23: group; 0-7 Q, 8-15 K, 16-23 V
  const int h = g & 7;
  float rn[4];
  #pragma unroll
  for (int ni = 0; ni < 4; ni++) {
    float ss = 0.f;
    #pragma unroll
    for (int mi = 0; mi < 2; mi++)
      #pragma unroll
      for (int r = 0; r < 4; r++) ss += acc[mi][ni][r] * acc[mi][ni][r];
    ss += __shfl_xor(ss, 16, 64);
    ss += __shfl_xor(ss, 32, 64);
    rn[ni] = rsqrtf(ss * (1.0f / HD) + EPS);
    if (g < 8) rn[ni] *= 0.2550348190698169f;  // log2(e)/sqrt(32) folded into Q
  }

  if (g < 8) {  // Q: row layout [q][HD]
    ushort* dst = Qn + (size_t)(b * NH + h) * S * HD;
    #pragma unroll
    for (int mi = 0; mi < 2; mi++)
      #pragma unroll
      for (int ni = 0; ni < 4; ni++) {
        ushort4 u;
        u.x = f2bf(acc[mi][ni][0] * rn[ni]);
        u.y = f2bf(acc[mi][ni][1] * rn[ni]);
        u.z = f2bf(acc[mi][ni][2] * rn[ni]);
        u.w = f2bf(acc[mi][ni][3] * rn[ni]);
        *(ushort4*)&dst[(size_t)(n0 + ni * 16 + col) * HD + mi * 16 + quad * 4] = u;
      }
  } else if (g < 16) {  // K: fragment panels
    // key = n0 + ni*16 + col; ch = mi*16 + quad*4 + r
    ushort* dst = Kn + (size_t)(b * NH + h) * S * HD + (size_t)(n0 >> 5) * 1024;
    #pragma unroll
    for (int mi = 0; mi < 2; mi++)
      #pragma unroll
      for (int ni = 0; ni < 4; ni++) {
        ushort4 u;
        u.x = f2bf(acc[mi][ni][0] * rn[ni]);
        u.y = f2bf(acc[mi][ni][1] * rn[ni]);
        u.z = f2bf(acc[mi][ni][2] * rn[ni]);
        u.w = f2bf(acc[mi][ni][3] * rn[ni]);
        *(ushort4*)&dst[(ni >> 1) * 1024 + mi * 512 + ((ni & 1) * 16 + col) * 16 +
                        (quad >> 1) * 8 + (quad & 1) * 4] = u;
      }
  } else {  // V: fragment panels (d = mi*16+quad*4+r, key = n0+ni*16+col)
    ushort* dst = Vt + (size_t)(b * NH + h) * HD * S + (size_t)(n0 >> 6) * 2048;
    #pragma unroll
    for (int mi = 0; mi < 2; mi++)
      #pragma unroll
      for (int ni = 0; ni < 4; ni++)
        #pragma unroll
        for (int r = 0; r < 4; r++)
          dst[ni * 512 + (mi * 16 + quad * 4 + r) * 16 + col] =
              f2bf(acc[mi][ni][r] * rn[ni]);
  }
}

// ---------------- MFMA attention: 32x32 tiles, P in registers ----------------
// Single 32x32 q-tile per wave (84 regs = 52 VGPR + 32 AGPR -> 6 waves/SIMD
// resident) + KSPLIT=4 grid (2048 blocks = 8 blocks/CU) to actually SUPPLY
// those waves: 24 waves/CU vs R5's 16 -- the VALU/dep-stall bound needs TLP.
// S^T = K.Q^T via mfma_32x32x16 (Q pre-scaled -> exp2 direct). P rebuilt into
// the PV operand fragment in registers (T12). K/V read from fragment-ordered
// panels (dense base+lane*16B loads), K and V prefetched one 64-key tile
// ahead. Denominator via ones-MFMA (keeps the adds on the idle MFMA pipe).
// DO NOT raise launch_bounds: VGPR+AGPR share one file (R2/R4 spilled at
// (256,8)). Bijective XCD swizzle: each XCD owns 8 complete (b,kp,h) groups
// (K/V ~1MB, L2-resident; FETCH ~= unique bytes, verified R3/R5). Zero LDS.
__global__ __launch_bounds__(256, 4) void attn_kernel(const ushort* __restrict__ Qn,
                                                      const ushort* __restrict__ Kn,
                                                      const ushort* __restrict__ Vt,
                                                      float* __restrict__ accP,
                                                      float* __restrict__ lP) {
  const int NWG = (S / 128) * NH * KSPLIT * 2;  // 2048
  const int bid = blockIdx.x;
  const int id = (bid & 7) * (NWG / 8) + (bid >> 3);
  const int qt = id & 31;       // 32 q-tiles of 128 rows
  const int grp = id >> 5;      // ((b*KSPLIT + kp) << 3) | h
  const int h = grp & 7;
  const int kp = (grp >> 3) & (KSPLIT - 1);
  const int b = grp >> 5;       // (grp>>3)/KSPLIT with KSPLIT=4
  const int wid = threadIdx.x >> 6, lane = threadIdx.x & 63;
  const int ln = lane & 31, hi = lane >> 5;
  const int q0 = qt * 128 + wid * 32;

  const ushort* Qh = Qn + (size_t)(b * NH + h) * S * HD;

  // Q as B-frag: col=q=ln, ch = half*16 + 8*hi + j
  bf16x8 qf0 = *(const bf16x8*)&Qh[(size_t)(q0 + ln) * HD + hi * 8];
  bf16x8 qf1 = *(const bf16x8*)&Qh[(size_t)(q0 + ln) * HD + 16 + hi * 8];

  const u16x8 ou = {0x3F80, 0x3F80, 0x3F80, 0x3F80, 0x3F80, 0x3F80, 0x3F80, 0x3F80};
  const bf16x8 ones = __builtin_bit_cast(bf16x8, ou);
  const f32x16 z = {};
  f32x16 acc = {};   // out^T tile: row=d, col=q
  f32x16 accl = {};  // softmax denom (all rows identical)

  const int kt0 = kp * (S / KSPLIT);
  // fragment-panel bases; every frag load = base + frag_offset + loff
  const int loff = (ln * 2 + hi) * 8;
  const ushort* Kp = Kn + (size_t)(b * NH + h) * S * HD + (size_t)kt0 * 32 + loff;
  const ushort* Vp = Vt + (size_t)(b * NH + h) * HD * S + (size_t)kt0 * 32 + loff;

  bf16x8 kf0 = *(const bf16x8*)&Kp[0];
  bf16x8 kf1 = *(const bf16x8*)&Kp[512];
  bf16x8 kf2 = *(const bf16x8*)&Kp[1024];
  bf16x8 kf3 = *(const bf16x8*)&Kp[1536];
  bf16x8 vf0 = *(const bf16x8*)&Vp[0];
  bf16x8 vf1 = *(const bf16x8*)&Vp[512];
  bf16x8 vf2 = *(const bf16x8*)&Vp[1024];
  bf16x8 vf3 = *(const bf16x8*)&Vp[1536];

  #pragma unroll 1
  for (int it = 0; it < S / KSPLIT / 64; ++it) {   // 16 iters of 64 keys
    Kp += 2048;
    Vp += 2048;

    // keys +0..31
    f32x16 s = __builtin_amdgcn_mfma_f32_32x32x16_bf16(kf0, qf0, z, 0, 0, 0);
    s = __builtin_amdgcn_mfma_f32_32x32x16_bf16(kf1, qf1, s, 0, 0, 0);
    kf0 = *(const bf16x8*)&Kp[0];       // prefetch next tile (overread stays in workspace)
    kf1 = *(const bf16x8*)&Kp[512];
    bf16x8 pf0, pf1;
    s_to_pf(s, pf0, pf1);
    acc = __builtin_amdgcn_mfma_f32_32x32x16_bf16(vf0, pf0, acc, 0, 0, 0);
    accl = __builtin_amdgcn_mfma_f32_32x32x16_bf16(ones, pf0, accl, 0, 0, 0);
    acc = __builtin_amdgcn_mfma_f32_32x32x16_bf16(vf1, pf1, acc, 0, 0, 0);
    accl = __builtin_amdgcn_mfma_f32_32x32x16_bf16(ones, pf1, accl, 0, 0, 0);

    // keys +32..63
    f32x16 t = __builtin_amdgcn_mfma_f32_32x32x16_bf16(kf2, qf0, z, 0, 0, 0);
    t = __builtin_amdgcn_mfma_f32_32x32x16_bf16(kf3, qf1, t, 0, 0, 0);
    kf2 = *(const bf16x8*)&Kp[1024];
    kf3 = *(const bf16x8*)&Kp[1536];
    bf16x8 pf2, pf3;
    s_to_pf(t, pf2, pf3);
    acc = __builtin_amdgcn_mfma_f32_32x32x16_bf16(vf2, pf2, acc, 0, 0, 0);
    accl = __builtin_amdgcn_mfma_f32_32x32x16_bf16(ones, pf2, accl, 0, 0, 0);
    acc = __builtin_amdgcn_mfma_f32_32x32x16_bf16(vf3, pf3, acc, 0, 0, 0);
    accl = __builtin_amdgcn_mfma_f32_32x32x16_bf16(ones, pf3, accl, 0, 0, 0);

    vf0 = *(const bf16x8*)&Vp[0];       // prefetch next tile's V (consumed mid-next-iter)
    vf1 = *(const bf16x8*)&Vp[512];
    vf2 = *(const bf16x8*)&Vp[1024];
    vf3 = *(const bf16x8*)&Vp[1536];
  }

  // acc[r]: d = (r&3) + 8*(r>>2) + 4*hi, q = ln
  float* ap = accP + ((size_t)((kp * 2 + b) * NH + h)) * S * HD;
  const size_t qrow = (size_t)(q0 + ln) * HD;
  #pragma unroll
  for (int g = 0; g < 4; g++) {
    float4 u;
    u.x = acc[4 * g + 0];
    u.y = acc[4 * g + 1];
    u.z = acc[4 * g + 2];
    u.w = acc[4 * g + 3];
    *(float4*)&ap[qrow + g * 8 + hi * 4] = u;
  }
  if (hi == 0)
    lP[((size_t)((kp * 2 + b) * NH + h)) * S + q0 + ln] = accl[0];
}

// ---------------- combine K-split partials -> Yt [b][s][256] bf16 ------------
__global__ __launch_bounds__(256) void combine_kernel(const float* __restrict__ accP,
                                                      const float* __restrict__ lP,
                                                      ushort* __restrict__ Yt) {
  const int tid = blockIdx.x * 256 + threadIdx.x;
  const int dg = tid & 7;
  const int q = (tid >> 3) & (S - 1);
  const int h = (tid >> 15) & 7;
  const int b = tid >> 18;
  const size_t i0 = ((size_t)(b * NH + h)) * S + q;
  const size_t part = (size_t)2 * NH * S;
  float sx = 0.f, sy = 0.f, sz = 0.f, sw = 0.f, L = 0.f;
  #pragma unroll
  for (int p = 0; p < KSPLIT; p++) {
    const float4 a = *(const float4*)&accP[(size_t)p * part * HD + i0 * HD + dg * 4];
    sx += a.x; sy += a.y; sz += a.z; sw += a.w;
    L += lP[(size_t)p * part + i0];
  }
  const float rl = 1.0f / L;
  ushort4 o;
  o.x = f2bf(sx * rl);
  o.y = f2bf(sy * rl);
  o.z = f2bf(sz * rl);
  o.w = f2bf(sw * rl);
  *(ushort4*)&Yt[((size_t)b * S + q) * CIN + h * HD + dg * 4] = o;
}

// ---------------- conv2: OUT[b][m][s] fp32 = Wo . Yt, fused mp_add -----------
__global__ __launch_bounds__(256) void conv2_kernel(const ushort* __restrict__ W,
                                                    const ushort* __restrict__ Bm,
                                                    const float* __restrict__ RES,
                                                    float* __restrict__ OUT) {
  const int b = blockIdx.z;
  const int wid = threadIdx.x >> 6, lane = threadIdx.x & 63;
  const int col = lane & 15, quad = lane >> 4;
  const int m0 = blockIdx.y * 64 + (wid >> 1) * 32;
  const int n0 = blockIdx.x * 128 + (wid & 1) * 64;
  const ushort* Bb = Bm + (size_t)b * S * CIN;
  f32x4 acc[2][4] = {};
  #pragma unroll
  for (int k0 = 0; k0 < CIN; k0 += 32) {
    bf16x8 af[2], bf[4];
    #pragma unroll
    for (int mi = 0; mi < 2; mi++)
      af[mi] = *(const bf16x8*)&W[(size_t)(m0 + mi * 16 + col) * CIN + k0 + quad * 8];
    #pragma unroll
    for (int ni = 0; ni < 4; ni++)
      bf[ni] = *(const bf16x8*)&Bb[(size_t)(n0 + ni * 16 + col) * CIN + k0 + quad * 8];
    #pragma unroll
    for (int mi = 0; mi < 2; mi++)
      #pragma unroll
      for (int ni = 0; ni < 4; ni++)
        acc[mi][ni] = __builtin_amdgcn_mfma_f32_16x16x32_bf16(af[mi], bf[ni], acc[mi][ni], 0, 0, 0);
  }
  const float tc = 0.3f, om = 0.7f, inv = 1.3130643285972254f;
  #pragma unroll
  for (int mi = 0; mi < 2; mi++)
    #pragma unroll
    for (int ni = 0; ni < 4; ni++)
      #pragma unroll
      for (int r = 0; r < 4; r++) {
        const size_t idx = ((size_t)(b * CIN + m0 + mi * 16 + quad * 4 + r)) * S + n0 + ni * 16 + col;
        OUT[idx] = (om * RES[idx] + tc * acc[mi][ni][r]) * inv;
      }
}

// ---------------- launch ----------------
extern "C" void kernel_launch(void* const* d_in, const int* in_sizes, int n_in,
                              void* d_out, int out_size, void* d_ws, size_t ws_size,
                              hipStream_t stream) {
  const float* x = (const float*)d_in[0];
  const float* w_qkv = (const float*)d_in[1];
  const float* w_out = (const float*)d_in[2];
  float* out = (float*)d_out;

  ushort* p = (ushort*)d_ws;
  ushort* wqb = p; p += (size_t)C3 * CIN;
  ushort* wob = p; p += (size_t)CIN * CIN;
  ushort* Qn = p; p += (size_t)2 * NH * S * HD;
  ushort* Kn = p; p += (size_t)2 * NH * S * HD;
  ushort* Vt = p; p += (size_t)2 * NH * S * HD;
  ushort* Yt = p; p += (size_t)2 * S * CIN;
  // Region R: Xt (4.2 MB bf16) dies after conv1_fused; accP fp32
  // (KSPLIT*2*8*4096*32 floats = 33.5 MB) aliases the same region.
  ushort* R = p; p += (size_t)KSPLIT * 2 * NH * S * HD * 2;  // 33.5 MB
  ushort* Xt = R;
  float* accP = (float*)R;
  float* lP = (float*)p;  // KSPLIT*2*8*4096 floats = 1 MB

  wnorm_kernel<<<(C3 + CIN) / 4, 256, 0, stream>>>(w_qkv, w_out, wqb, wob);
  xt_kernel<<<dim3(S / 64, CIN / 64, 2), 256, 0, stream>>>(x, Xt);
  conv1_fused_kernel<<<dim3(S / 128, C3 / 64, 2), 256, 0, stream>>>(wqb, Xt, Qn, Kn, Vt);
  attn_kernel<<<(S / 128) * NH * KSPLIT * 2, 256, 0, stream>>>(Qn, Kn, Vt, accP, lP);
  combine_kernel<<<2048, 256, 0, stream>>>(accP, lP, Yt);
  conv2_kernel<<<dim3(S / 128, CIN / 64, 2), 256, 0, stream>>>(wob, Yt, x, out);
}

// Round 7
// 162.708 us; speedup vs baseline: 1.0006x; 1.0006x over previous
//
#include <hip/hip_runtime.h>
#include <hip/hip_bf16.h>
#include <math.h>

#define S 4096
#define CIN 256
#define C3 768
#define NH 8
#define HD 32
#define KSPLIT 4

static constexpr float EPS = 1e-4f;

typedef __attribute__((ext_vector_type(8))) __bf16 bf16x8;
typedef __attribute__((ext_vector_type(4))) float f32x4;
typedef __attribute__((ext_vector_type(16))) float f32x16;
typedef __attribute__((ext_vector_type(4))) unsigned u32x4;

static inline __device__ ushort f2bf(float f) {  // RN-even
  unsigned u = __float_as_uint(f);
  return (ushort)((u + 0x7fffu + ((u >> 16) & 1u)) >> 16);
}

// v_cvt_pk_bf16_f32: dst.lo16 = bf16(lo), dst.hi16 = bf16(hi); RNE (no builtin)
static inline __device__ unsigned cvt_pk_bf16(float lo, float hi) {
  unsigned r;
  asm("v_cvt_pk_bf16_f32 %0, %1, %2" : "=v"(r) : "v"(lo), "v"(hi));
  return r;
}
// v_permlane32_swap_b32: a.hi32lanes <-> b.lo32lanes.
static inline __device__ void plane32_swap(unsigned& a, unsigned& b) {
  asm("v_permlane32_swap_b32 %0, %1" : "+v"(a), "+v"(b));
}

#define EXP2 __builtin_amdgcn_exp2f

// Convert one 32x32 QK score tile (D-layout: col=q=lane&31, row=k=(r&3)+8*(r>>2)+4*hi)
// to two PV operand fragments (col/row=q, k = frag*8 elements at 8*hi+j) fully
// in registers: 8 cvt_pk + 4 permlane32_swap. plo covers k 0..15, phi 16..31.
// Accumulates the lane's 16 exp values into lacc (softmax denominator partial;
// full denom for q=ln is lacc + shfl_xor(lacc,32)).
static inline __device__ void s_to_pf(const f32x16 s, bf16x8& plo, bf16x8& phi,
                                      float& lacc) {
  float e0 = EXP2(s[0]), e1 = EXP2(s[1]), e2 = EXP2(s[2]), e3 = EXP2(s[3]);
  float e4 = EXP2(s[4]), e5 = EXP2(s[5]), e6 = EXP2(s[6]), e7 = EXP2(s[7]);
  float e8 = EXP2(s[8]), e9 = EXP2(s[9]), e10 = EXP2(s[10]), e11 = EXP2(s[11]);
  float e12 = EXP2(s[12]), e13 = EXP2(s[13]), e14 = EXP2(s[14]), e15 = EXP2(s[15]);
  lacc += (((e0 + e1) + (e2 + e3)) + ((e4 + e5) + (e6 + e7))) +
          (((e8 + e9) + (e10 + e11)) + ((e12 + e13) + (e14 + e15)));
  unsigned c0 = cvt_pk_bf16(e0, e1);    // hi0:k(0,1)   hi1:k(4,5)
  unsigned c1 = cvt_pk_bf16(e2, e3);    // hi0:k(2,3)   hi1:k(6,7)
  unsigned c2 = cvt_pk_bf16(e4, e5);    // hi0:k(8,9)   hi1:k(12,13)
  unsigned c3 = cvt_pk_bf16(e6, e7);    // hi0:k(10,11) hi1:k(14,15)
  plane32_swap(c0, c2);
  plane32_swap(c1, c3);
  u32x4 lo4 = {c0, c1, c2, c3};
  plo = __builtin_bit_cast(bf16x8, lo4);
  unsigned c4 = cvt_pk_bf16(e8, e9);
  unsigned c5 = cvt_pk_bf16(e10, e11);
  unsigned c6 = cvt_pk_bf16(e12, e13);
  unsigned c7 = cvt_pk_bf16(e14, e15);
  plane32_swap(c4, c6);
  plane32_swap(c5, c7);
  u32x4 hi4 = {c4, c5, c6, c7};
  phi = __builtin_bit_cast(bf16x8, hi4);
}

// ---------------- weight norm (both weights, one launch) ---------------------
__global__ __launch_bounds__(256) void wnorm_kernel(const float* __restrict__ w_qkv,
                                                    const float* __restrict__ w_out,
                                                    ushort* __restrict__ wqb,
                                                    ushort* __restrict__ wob) {
  const int row = blockIdx.x * 4 + (threadIdx.x >> 6);
  const int lane = threadIdx.x & 63;
  const bool is_q = row < C3;
  const float* wr = (is_q ? w_qkv + (size_t)row * CIN : w_out + (size_t)(row - C3) * CIN);
  float v0 = wr[lane], v1 = wr[lane + 64], v2 = wr[lane + 128], v3 = wr[lane + 192];
  float ss = v0 * v0 + v1 * v1 + v2 * v2 + v3 * v3;
  #pragma unroll
  for (int off = 32; off > 0; off >>= 1) ss += __shfl_down(ss, off, 64);
  ss = __shfl(ss, 0, 64);
  const float scale = 1.0f / (sqrtf(ss) + 16.0f * EPS);
  ushort* whr = (is_q ? wqb + (size_t)row * CIN : wob + (size_t)(row - C3) * CIN);
  whr[lane] = f2bf(v0 * scale);
  whr[lane + 64] = f2bf(v1 * scale);
  whr[lane + 128] = f2bf(v2 * scale);
  whr[lane + 192] = f2bf(v3 * scale);
}

// ---------------- X [b][c][s] fp32 -> Xt [b][s][c] bf16 ----------------------
__global__ __launch_bounds__(256) void xt_kernel(const float* __restrict__ X,
                                                 ushort* __restrict__ Xt) {
  const int b = blockIdx.z;
  const int s0 = blockIdx.x * 64, c0 = blockIdx.y * 64;
  __shared__ ushort T[64][72];
  const int tc = threadIdx.x >> 4;
  const int ts = threadIdx.x & 15;
  #pragma unroll
  for (int i = 0; i < 4; i++) {
    const float4 v = *(const float4*)&X[((size_t)(b * CIN + c0 + tc + 16 * i)) * S + s0 + ts * 4];
    ushort4 u;
    u.x = f2bf(v.x); u.y = f2bf(v.y); u.z = f2bf(v.z); u.w = f2bf(v.w);
    *(ushort4*)&T[tc + 16 * i][ts * 4] = u;
  }
  __syncthreads();
  #pragma unroll
  for (int i = 0; i < 4; i++) {
    const int sr = tc + 16 * i;
    ushort4 u;
    u.x = T[ts * 4 + 0][sr];
    u.y = T[ts * 4 + 1][sr];
    u.z = T[ts * 4 + 2][sr];
    u.w = T[ts * 4 + 3][sr];
    *(ushort4*)&Xt[((size_t)b * S + s0 + sr) * CIN + c0 + ts * 4] = u;
  }
}

// ---------------- conv1 fused with pixel-norm + layout fan-out ---------------
// Per-wave tile 32m x 32n (m = one full 32-ch head group so pixel-norm stays a
// wave-local reduction); block = 4 waves covering 32m x 128n. Grid (32,24,2) =
// 1536 blocks = 6 blocks/CU (was 768 = 3/CU -- latency-exposed). Outputs:
// Q rows [bh][q][HD]; K/V in MFMA-fragment-ordered panels (see R3):
//   Kpan: [bh][key>>5][half][key&31][hi][8]
//   Vpan: [bh][key>>6][kc][d][hi][8]
__global__ __launch_bounds__(256) void conv1_fused_kernel(const ushort* __restrict__ W,
                                                          const ushort* __restrict__ Bm,
                                                          ushort* __restrict__ Qn,
                                                          ushort* __restrict__ Kn,
                                                          ushort* __restrict__ Vt) {
  const int b = blockIdx.z;
  const int wid = threadIdx.x >> 6, lane = threadIdx.x & 63;
  const int col = lane & 15, quad = lane >> 4;
  const int m0 = blockIdx.y * 32;                    // one head group per block-row
  const int n0 = blockIdx.x * 128 + wid * 32;        // 32 pixels per wave
  const ushort* Bb = Bm + (size_t)b * S * CIN;
  f32x4 acc[2][2] = {};
  #pragma unroll
  for (int k0 = 0; k0 < CIN; k0 += 32) {
    bf16x8 af[2], bf[2];
    #pragma unroll
    for (int mi = 0; mi < 2; mi++)
      af[mi] = *(const bf16x8*)&W[(size_t)(m0 + mi * 16 + col) * CIN + k0 + quad * 8];
    #pragma unroll
    for (int ni = 0; ni < 2; ni++)
      bf[ni] = *(const bf16x8*)&Bb[(size_t)(n0 + ni * 16 + col) * CIN + k0 + quad * 8];
    #pragma unroll
    for (int mi = 0; mi < 2; mi++)
      #pragma unroll
      for (int ni = 0; ni < 2; ni++)
        acc[mi][ni] = __builtin_amdgcn_mfma_f32_16x16x32_bf16(af[mi], bf[ni], acc[mi][ni], 0, 0, 0);
  }

  const int g = m0 >> 5;   // 0..23: group; 0-7 Q, 8-15 K, 16-23 V
  const int h = g & 7;
  float rn[2];
  #pragma unroll
  for (int ni = 0; ni < 2; ni++) {
    float ss = 0.f;
    #pragma unroll
    for (int mi = 0; mi < 2; mi++)
      #pragma unroll
      for (int r = 0; r < 4; r++) ss += acc[mi][ni][r] * acc[mi][ni][r];
    ss += __shfl_xor(ss, 16, 64);
    ss += __shfl_xor(ss, 32, 64);
    rn[ni] = rsqrtf(ss * (1.0f / HD) + EPS);
    if (g < 8) rn[ni] *= 0.2550348190698169f;  // log2(e)/sqrt(32) folded into Q
  }

  if (g < 8) {  // Q: row layout [q][HD]
    ushort* dst = Qn + (size_t)(b * NH + h) * S * HD;
    #pragma unroll
    for (int mi = 0; mi < 2; mi++)
      #pragma unroll
      for (int ni = 0; ni < 2; ni++) {
        ushort4 u;
        u.x = f2bf(acc[mi][ni][0] * rn[ni]);
        u.y = f2bf(acc[mi][ni][1] * rn[ni]);
        u.z = f2bf(acc[mi][ni][2] * rn[ni]);
        u.w = f2bf(acc[mi][ni][3] * rn[ni]);
        *(ushort4*)&dst[(size_t)(n0 + ni * 16 + col) * HD + mi * 16 + quad * 4] = u;
      }
  } else if (g < 16) {  // K: fragment panels (key = n0+ni*16+col; ch = mi*16+quad*4+r)
    ushort* dst = Kn + (size_t)(b * NH + h) * S * HD + (size_t)(n0 >> 5) * 1024;
    #pragma unroll
    for (int mi = 0; mi < 2; mi++)
      #pragma unroll
      for (int ni = 0; ni < 2; ni++) {
        ushort4 u;
        u.x = f2bf(acc[mi][ni][0] * rn[ni]);
        u.y = f2bf(acc[mi][ni][1] * rn[ni]);
        u.z = f2bf(acc[mi][ni][2] * rn[ni]);
        u.w = f2bf(acc[mi][ni][3] * rn[ni]);
        *(ushort4*)&dst[mi * 512 + (ni * 16 + col) * 16 +
                        (quad >> 1) * 8 + (quad & 1) * 4] = u;
      }
  } else {  // V: fragment panels (d = mi*16+quad*4+r, key = n0+ni*16+col)
    ushort* dst = Vt + (size_t)(b * NH + h) * HD * S + (size_t)(n0 >> 6) * 2048;
    const int kcbase = (n0 & 32) >> 4;  // which 16-key slot inside the 64-key panel
    #pragma unroll
    for (int mi = 0; mi < 2; mi++)
      #pragma unroll
      for (int ni = 0; ni < 2; ni++)
        #pragma unroll
        for (int r = 0; r < 4; r++)
          dst[(kcbase + ni) * 512 + (mi * 16 + quad * 4 + r) * 16 + col] =
              f2bf(acc[mi][ni][r] * rn[ni]);
  }
}

// ---------------- MFMA attention: dual 32x32 q-tiles per wave (R5) -----------
// S^T = K.Q^T via mfma_32x32x16 (Q pre-scaled -> exp2 direct). P rebuilt into
// the PV operand fragment in registers (T12). K/V read from fragment-ordered
// panels (dense base+lane*16B loads), prefetched one 32-key tile ahead.
// Each wave owns TWO q-tiles sharing the same K/V frags (2x per-wave ILP to
// fill the QK->exp2->cvt->PV dependency stalls). Denominator via VALU adds in
// s_to_pf. ~96 regs at __launch_bounds__(256,4) -- DO NOT raise waves/EU:
// VGPR+AGPR share one file (R2/R4 spilled at (256,8)); R6 showed single-tile
// +TLP loses to dual-tile ILP. KSPLIT=4, grid 1024 = 4 blocks/CU.
// Bijective XCD swizzle: each XCD owns complete (b,kp,h) groups. Zero LDS.
__global__ __launch_bounds__(256, 4) void attn_kernel(const ushort* __restrict__ Qn,
                                                      const ushort* __restrict__ Kn,
                                                      const ushort* __restrict__ Vt,
                                                      float* __restrict__ accP,
                                                      float* __restrict__ lP) {
  const int NWG = (S / 256) * NH * KSPLIT * 2;  // 1024
  const int bid = blockIdx.x;
  const int id = (bid & 7) * (NWG / 8) + (bid >> 3);
  const int qt = id & 15;       // 16 q-tiles of 256 rows
  const int grp = id >> 4;      // ((b*KSPLIT + kp) << 3) | h
  const int h = grp & 7;
  const int kp = (grp >> 3) & (KSPLIT - 1);
  const int b = (grp >> 3) / KSPLIT;
  const int wid = threadIdx.x >> 6, lane = threadIdx.x & 63;
  const int ln = lane & 31, hi = lane >> 5;
  const int qA = qt * 256 + wid * 64;   // tile A rows qA..qA+31
  const int qB = qA + 32;               // tile B rows qB..qB+31

  const ushort* Qh = Qn + (size_t)(b * NH + h) * S * HD;

  // Q as B-frag: col=q=ln, ch = half*16 + 8*hi + j
  bf16x8 qfA0 = *(const bf16x8*)&Qh[(size_t)(qA + ln) * HD + hi * 8];
  bf16x8 qfA1 = *(const bf16x8*)&Qh[(size_t)(qA + ln) * HD + 16 + hi * 8];
  bf16x8 qfB0 = *(const bf16x8*)&Qh[(size_t)(qB + ln) * HD + hi * 8];
  bf16x8 qfB1 = *(const bf16x8*)&Qh[(size_t)(qB + ln) * HD + 16 + hi * 8];

  const f32x16 z = {};
  f32x16 accA = {}, accB = {};  // out^T tiles: row=d, col=q
  float laccA = 0.f, laccB = 0.f;

  const int kt0 = kp * (S / KSPLIT);
  // fragment-panel bases; every frag load = base + frag_offset + loff
  const int loff = (ln * 2 + hi) * 8;
  const ushort* Kp = Kn + (size_t)(b * NH + h) * S * HD + (size_t)kt0 * 32 + loff;
  const ushort* Vp = Vt + (size_t)(b * NH + h) * HD * S + (size_t)kt0 * 32 + loff;

  bf16x8 kf0 = *(const bf16x8*)&Kp[0];
  bf16x8 kf1 = *(const bf16x8*)&Kp[512];
  bf16x8 vf0 = *(const bf16x8*)&Vp[0];
  bf16x8 vf1 = *(const bf16x8*)&Vp[512];

  #pragma unroll 1
  for (int it = 0; it < S / KSPLIT / 32; ++it) {   // 32-key steps
    f32x16 sA = __builtin_amdgcn_mfma_f32_32x32x16_bf16(kf0, qfA0, z, 0, 0, 0);
    sA = __builtin_amdgcn_mfma_f32_32x32x16_bf16(kf1, qfA1, sA, 0, 0, 0);
    f32x16 sB = __builtin_amdgcn_mfma_f32_32x32x16_bf16(kf0, qfB0, z, 0, 0, 0);
    sB = __builtin_amdgcn_mfma_f32_32x32x16_bf16(kf1, qfB1, sB, 0, 0, 0);
    Kp += 1024;
    kf0 = *(const bf16x8*)&Kp[0];      // prefetch next tile's K (overread stays in ws)
    kf1 = *(const bf16x8*)&Kp[512];

    bf16x8 pfA0, pfA1;
    s_to_pf(sA, pfA0, pfA1, laccA);
    accA = __builtin_amdgcn_mfma_f32_32x32x16_bf16(vf0, pfA0, accA, 0, 0, 0);
    accA = __builtin_amdgcn_mfma_f32_32x32x16_bf16(vf1, pfA1, accA, 0, 0, 0);

    bf16x8 pfB0, pfB1;
    s_to_pf(sB, pfB0, pfB1, laccB);
    accB = __builtin_amdgcn_mfma_f32_32x32x16_bf16(vf0, pfB0, accB, 0, 0, 0);
    accB = __builtin_amdgcn_mfma_f32_32x32x16_bf16(vf1, pfB1, accB, 0, 0, 0);

    Vp += 1024;
    vf0 = *(const bf16x8*)&Vp[0];      // prefetch next tile's V
    vf1 = *(const bf16x8*)&Vp[512];
  }

  // acc[r]: d = (r&3) + 8*(r>>2) + 4*hi, q = ln
  float* ap = accP + ((size_t)((kp * 2 + b) * NH + h)) * S * HD;
  const size_t rowA = (size_t)(qA + ln) * HD;
  const size_t rowB = (size_t)(qB + ln) * HD;
  #pragma unroll
  for (int g = 0; g < 4; g++) {
    float4 u;
    u.x = accA[4 * g + 0];
    u.y = accA[4 * g + 1];
    u.z = accA[4 * g + 2];
    u.w = accA[4 * g + 3];
    *(float4*)&ap[rowA + g * 8 + hi * 4] = u;
    float4 v;
    v.x = accB[4 * g + 0];
    v.y = accB[4 * g + 1];
    v.z = accB[4 * g + 2];
    v.w = accB[4 * g + 3];
    *(float4*)&ap[rowB + g * 8 + hi * 4] = v;
  }
  const float lsA = laccA + __shfl_xor(laccA, 32, 64);
  const float lsB = laccB + __shfl_xor(laccB, 32, 64);
  if (hi == 0) {
    float* lp = lP + ((size_t)((kp * 2 + b) * NH + h)) * S;
    lp[qA + ln] = lsA;
    lp[qB + ln] = lsB;
  }
}

// ---------------- combine K-split partials -> Yt [b][s][256] bf16 ------------
__global__ __launch_bounds__(256) void combine_kernel(const float* __restrict__ accP,
                                                      const float* __restrict__ lP,
                                                      ushort* __restrict__ Yt) {
  const int tid = blockIdx.x * 256 + threadIdx.x;
  const int dg = tid & 7;
  const int q = (tid >> 3) & (S - 1);
  const int h = (tid >> 15) & 7;
  const int b = tid >> 18;
  const size_t i0 = ((size_t)(b * NH + h)) * S + q;
  const size_t part = (size_t)2 * NH * S;
  float sx = 0.f, sy = 0.f, sz = 0.f, sw = 0.f, L = 0.f;
  #pragma unroll
  for (int p = 0; p < KSPLIT; p++) {
    const float4 a = *(const float4*)&accP[(size_t)p * part * HD + i0 * HD + dg * 4];
    sx += a.x; sy += a.y; sz += a.z; sw += a.w;
    L += lP[(size_t)p * part + i0];
  }
  const float rl = 1.0f / L;
  ushort4 o;
  o.x = f2bf(sx * rl);
  o.y = f2bf(sy * rl);
  o.z = f2bf(sz * rl);
  o.w = f2bf(sw * rl);
  *(ushort4*)&Yt[((size_t)b * S + q) * CIN + h * HD + dg * 4] = o;
}

// ---------------- conv2: OUT[b][m][s] fp32 = Wo . Yt, fused mp_add -----------
// Per-wave tile 16m x 16n (acc = one f32x4); block = 4 waves covering
// 16m x 64n. Grid (64,16,2) = 2048 blocks = 8 blocks/CU (was 256 = 1 block/CU
// = 1 wave/SIMD -- the whole kernel was exposed load latency).
__global__ __launch_bounds__(256) void conv2_kernel(const ushort* __restrict__ W,
                                                    const ushort* __restrict__ Bm,
                                                    const float* __restrict__ RES,
                                                    float* __restrict__ OUT) {
  const int b = blockIdx.z;
  const int wid = threadIdx.x >> 6, lane = threadIdx.x & 63;
  const int col = lane & 15, quad = lane >> 4;
  const int m0 = blockIdx.y * 16;
  const int n0 = blockIdx.x * 64 + wid * 16;
  const ushort* Bb = Bm + (size_t)b * S * CIN;
  f32x4 acc = {};
  #pragma unroll
  for (int k0 = 0; k0 < CIN; k0 += 32) {
    const bf16x8 af = *(const bf16x8*)&W[(size_t)(m0 + col) * CIN + k0 + quad * 8];
    const bf16x8 bf = *(const bf16x8*)&Bb[(size_t)(n0 + col) * CIN + k0 + quad * 8];
    acc = __builtin_amdgcn_mfma_f32_16x16x32_bf16(af, bf, acc, 0, 0, 0);
  }
  const float tc = 0.3f, om = 0.7f, inv = 1.3130643285972254f;
  #pragma unroll
  for (int r = 0; r < 4; r++) {
    const size_t idx = ((size_t)(b * CIN + m0 + quad * 4 + r)) * S + n0 + col;
    OUT[idx] = (om * RES[idx] + tc * acc[r]) * inv;
  }
}

// ---------------- launch ----------------
extern "C" void kernel_launch(void* const* d_in, const int* in_sizes, int n_in,
                              void* d_out, int out_size, void* d_ws, size_t ws_size,
                              hipStream_t stream) {
  const float* x = (const float*)d_in[0];
  const float* w_qkv = (const float*)d_in[1];
  const float* w_out = (const float*)d_in[2];
  float* out = (float*)d_out;

  ushort* p = (ushort*)d_ws;
  ushort* wqb = p; p += (size_t)C3 * CIN;
  ushort* wob = p; p += (size_t)CIN * CIN;
  ushort* Qn = p; p += (size_t)2 * NH * S * HD;
  ushort* Kn = p; p += (size_t)2 * NH * S * HD;
  ushort* Vt = p; p += (size_t)2 * NH * S * HD;
  ushort* Yt = p; p += (size_t)2 * S * CIN;
  // Region R: Xt (4.2 MB bf16) dies after conv1_fused; accP fp32
  // (KSPLIT*2*8*4096*32 floats = 33.5 MB) aliases the same region.
  ushort* R = p; p += (size_t)KSPLIT * 2 * NH * S * HD * 2;  // 33.5 MB
  ushort* Xt = R;
  float* accP = (float*)R;
  float* lP = (float*)p;  // KSPLIT*2*8*4096 floats = 1 MB

  wnorm_kernel<<<(C3 + CIN) / 4, 256, 0, stream>>>(w_qkv, w_out, wqb, wob);
  xt_kernel<<<dim3(S / 64, CIN / 64, 2), 256, 0, stream>>>(x, Xt);
  conv1_fused_kernel<<<dim3(S / 128, C3 / 32, 2), 256, 0, stream>>>(wqb, Xt, Qn, Kn, Vt);
  attn_kernel<<<(S / 256) * NH * KSPLIT * 2, 256, 0, stream>>>(Qn, Kn, Vt, accP, lP);
  combine_kernel<<<2048, 256, 0, stream>>>(accP, lP, Yt);
  conv2_kernel<<<dim3(S / 64, CIN / 16, 2), 256, 0, stream>>>(wob, Yt, x, out);
}

// Round 8
// 152.830 us; speedup vs baseline: 1.0653x; 1.0646x over previous
//
#include <hip/hip_runtime.h>
#include <hip/hip_bf16.h>
#include <math.h>

#define S 4096
#define CIN 256
#define C3 768
#define NH 8
#define HD 32
#define KSPLIT 4

static constexpr float EPS = 1e-4f;

typedef __attribute__((ext_vector_type(8))) __bf16 bf16x8;
typedef __attribute__((ext_vector_type(4))) float f32x4;
typedef __attribute__((ext_vector_type(16))) float f32x16;
typedef __attribute__((ext_vector_type(4))) unsigned u32x4;

static inline __device__ ushort f2bf(float f) {  // RN-even
  unsigned u = __float_as_uint(f);
  return (ushort)((u + 0x7fffu + ((u >> 16) & 1u)) >> 16);
}
static inline __device__ float bf2f(ushort u) {
  return __uint_as_float((unsigned)u << 16);
}

// v_cvt_pk_bf16_f32: dst.lo16 = bf16(lo), dst.hi16 = bf16(hi); RNE (no builtin)
static inline __device__ unsigned cvt_pk_bf16(float lo, float hi) {
  unsigned r;
  asm("v_cvt_pk_bf16_f32 %0, %1, %2" : "=v"(r) : "v"(lo), "v"(hi));
  return r;
}
// v_permlane32_swap_b32: a.hi32lanes <-> b.lo32lanes.
static inline __device__ void plane32_swap(unsigned& a, unsigned& b) {
  asm("v_permlane32_swap_b32 %0, %1" : "+v"(a), "+v"(b));
}

#define EXP2 __builtin_amdgcn_exp2f

// Convert one 32x32 QK score tile (D-layout: col=q=lane&31, row=k=(r&3)+8*(r>>2)+4*hi)
// to two PV operand fragments (col/row=q, k = frag*8 elements at 8*hi+j) fully
// in registers: 8 cvt_pk + 4 permlane32_swap. plo covers k 0..15, phi 16..31.
// Accumulates the lane's 16 exp values into lacc (softmax denominator partial;
// full denom for q=ln is lacc + shfl_xor(lacc,32)).
static inline __device__ void s_to_pf(const f32x16 s, bf16x8& plo, bf16x8& phi,
                                      float& lacc) {
  float e0 = EXP2(s[0]), e1 = EXP2(s[1]), e2 = EXP2(s[2]), e3 = EXP2(s[3]);
  float e4 = EXP2(s[4]), e5 = EXP2(s[5]), e6 = EXP2(s[6]), e7 = EXP2(s[7]);
  float e8 = EXP2(s[8]), e9 = EXP2(s[9]), e10 = EXP2(s[10]), e11 = EXP2(s[11]);
  float e12 = EXP2(s[12]), e13 = EXP2(s[13]), e14 = EXP2(s[14]), e15 = EXP2(s[15]);
  lacc += (((e0 + e1) + (e2 + e3)) + ((e4 + e5) + (e6 + e7))) +
          (((e8 + e9) + (e10 + e11)) + ((e12 + e13) + (e14 + e15)));
  unsigned c0 = cvt_pk_bf16(e0, e1);    // hi0:k(0,1)   hi1:k(4,5)
  unsigned c1 = cvt_pk_bf16(e2, e3);    // hi0:k(2,3)   hi1:k(6,7)
  unsigned c2 = cvt_pk_bf16(e4, e5);    // hi0:k(8,9)   hi1:k(12,13)
  unsigned c3 = cvt_pk_bf16(e6, e7);    // hi0:k(10,11) hi1:k(14,15)
  plane32_swap(c0, c2);
  plane32_swap(c1, c3);
  u32x4 lo4 = {c0, c1, c2, c3};
  plo = __builtin_bit_cast(bf16x8, lo4);
  unsigned c4 = cvt_pk_bf16(e8, e9);
  unsigned c5 = cvt_pk_bf16(e10, e11);
  unsigned c6 = cvt_pk_bf16(e12, e13);
  unsigned c7 = cvt_pk_bf16(e14, e15);
  plane32_swap(c4, c6);
  plane32_swap(c5, c7);
  u32x4 hi4 = {c4, c5, c6, c7};
  phi = __builtin_bit_cast(bf16x8, hi4);
}

// ---------------- weight norm (both weights, one launch) ---------------------
__global__ __launch_bounds__(256) void wnorm_kernel(const float* __restrict__ w_qkv,
                                                    const float* __restrict__ w_out,
                                                    ushort* __restrict__ wqb,
                                                    ushort* __restrict__ wob) {
  const int row = blockIdx.x * 4 + (threadIdx.x >> 6);
  const int lane = threadIdx.x & 63;
  const bool is_q = row < C3;
  const float* wr = (is_q ? w_qkv + (size_t)row * CIN : w_out + (size_t)(row - C3) * CIN);
  float v0 = wr[lane], v1 = wr[lane + 64], v2 = wr[lane + 128], v3 = wr[lane + 192];
  float ss = v0 * v0 + v1 * v1 + v2 * v2 + v3 * v3;
  #pragma unroll
  for (int off = 32; off > 0; off >>= 1) ss += __shfl_down(ss, off, 64);
  ss = __shfl(ss, 0, 64);
  const float scale = 1.0f / (sqrtf(ss) + 16.0f * EPS);
  ushort* whr = (is_q ? wqb + (size_t)row * CIN : wob + (size_t)(row - C3) * CIN);
  whr[lane] = f2bf(v0 * scale);
  whr[lane + 64] = f2bf(v1 * scale);
  whr[lane + 128] = f2bf(v2 * scale);
  whr[lane + 192] = f2bf(v3 * scale);
}

// ---------------- X [b][c][s] fp32 -> Xt [b][s][c] bf16 ----------------------
__global__ __launch_bounds__(256) void xt_kernel(const float* __restrict__ X,
                                                 ushort* __restrict__ Xt) {
  const int b = blockIdx.z;
  const int s0 = blockIdx.x * 64, c0 = blockIdx.y * 64;
  __shared__ ushort T[64][72];
  const int tc = threadIdx.x >> 4;
  const int ts = threadIdx.x & 15;
  #pragma unroll
  for (int i = 0; i < 4; i++) {
    const float4 v = *(const float4*)&X[((size_t)(b * CIN + c0 + tc + 16 * i)) * S + s0 + ts * 4];
    ushort4 u;
    u.x = f2bf(v.x); u.y = f2bf(v.y); u.z = f2bf(v.z); u.w = f2bf(v.w);
    *(ushort4*)&T[tc + 16 * i][ts * 4] = u;
  }
  __syncthreads();
  #pragma unroll
  for (int i = 0; i < 4; i++) {
    const int sr = tc + 16 * i;
    ushort4 u;
    u.x = T[ts * 4 + 0][sr];
    u.y = T[ts * 4 + 1][sr];
    u.z = T[ts * 4 + 2][sr];
    u.w = T[ts * 4 + 3][sr];
    *(ushort4*)&Xt[((size_t)b * S + s0 + sr) * CIN + c0 + ts * 4] = u;
  }
}

// ---------------- conv1 fused with pixel-norm + layout fan-out (R5) ----------
// Q written as [bh][q][HD] rows. K/V in MFMA-fragment-ordered panels:
//   Kpan: [bh][key>>5][half][key&31][hi][8]
//   Vpan: [bh][key>>6][kc][d][hi][8]
__global__ __launch_bounds__(256) void conv1_fused_kernel(const ushort* __restrict__ W,
                                                          const ushort* __restrict__ Bm,
                                                          ushort* __restrict__ Qn,
                                                          ushort* __restrict__ Kn,
                                                          ushort* __restrict__ Vt) {
  const int b = blockIdx.z;
  const int wid = threadIdx.x >> 6, lane = threadIdx.x & 63;
  const int col = lane & 15, quad = lane >> 4;
  const int m0 = blockIdx.y * 64 + (wid >> 1) * 32;  // 32-aligned: one head group
  const int n0 = blockIdx.x * 128 + (wid & 1) * 64;
  const ushort* Bb = Bm + (size_t)b * S * CIN;
  f32x4 acc[2][4] = {};
  #pragma unroll
  for (int k0 = 0; k0 < CIN; k0 += 32) {
    bf16x8 af[2], bf[4];
    #pragma unroll
    for (int mi = 0; mi < 2; mi++)
      af[mi] = *(const bf16x8*)&W[(size_t)(m0 + mi * 16 + col) * CIN + k0 + quad * 8];
    #pragma unroll
    for (int ni = 0; ni < 4; ni++)
      bf[ni] = *(const bf16x8*)&Bb[(size_t)(n0 + ni * 16 + col) * CIN + k0 + quad * 8];
    #pragma unroll
    for (int mi = 0; mi < 2; mi++)
      #pragma unroll
      for (int ni = 0; ni < 4; ni++)
        acc[mi][ni] = __builtin_amdgcn_mfma_f32_16x16x32_bf16(af[mi], bf[ni], acc[mi][ni], 0, 0, 0);
  }

  const int g = m0 >> 5;   // 0..23: group; 0-7 Q, 8-15 K, 16-23 V
  const int h = g & 7;
  float rn[4];
  #pragma unroll
  for (int ni = 0; ni < 4; ni++) {
    float ss = 0.f;
    #pragma unroll
    for (int mi = 0; mi < 2; mi++)
      #pragma unroll
      for (int r = 0; r < 4; r++) ss += acc[mi][ni][r] * acc[mi][ni][r];
    ss += __shfl_xor(ss, 16, 64);
    ss += __shfl_xor(ss, 32, 64);
    rn[ni] = rsqrtf(ss * (1.0f / HD) + EPS);
    if (g < 8) rn[ni] *= 0.2550348190698169f;  // log2(e)/sqrt(32) folded into Q
  }

  if (g < 8) {  // Q: row layout [q][HD]
    ushort* dst = Qn + (size_t)(b * NH + h) * S * HD;
    #pragma unroll
    for (int mi = 0; mi < 2; mi++)
      #pragma unroll
      for (int ni = 0; ni < 4; ni++) {
        ushort4 u;
        u.x = f2bf(acc[mi][ni][0] * rn[ni]);
        u.y = f2bf(acc[mi][ni][1] * rn[ni]);
        u.z = f2bf(acc[mi][ni][2] * rn[ni]);
        u.w = f2bf(acc[mi][ni][3] * rn[ni]);
        *(ushort4*)&dst[(size_t)(n0 + ni * 16 + col) * HD + mi * 16 + quad * 4] = u;
      }
  } else if (g < 16) {  // K: fragment panels (key = n0+ni*16+col; ch = mi*16+quad*4+r)
    ushort* dst = Kn + (size_t)(b * NH + h) * S * HD + (size_t)(n0 >> 5) * 1024;
    #pragma unroll
    for (int mi = 0; mi < 2; mi++)
      #pragma unroll
      for (int ni = 0; ni < 4; ni++) {
        ushort4 u;
        u.x = f2bf(acc[mi][ni][0] * rn[ni]);
        u.y = f2bf(acc[mi][ni][1] * rn[ni]);
        u.z = f2bf(acc[mi][ni][2] * rn[ni]);
        u.w = f2bf(acc[mi][ni][3] * rn[ni]);
        *(ushort4*)&dst[(ni >> 1) * 1024 + mi * 512 + ((ni & 1) * 16 + col) * 16 +
                        (quad >> 1) * 8 + (quad & 1) * 4] = u;
      }
  } else {  // V: fragment panels (d = mi*16+quad*4+r, key = n0+ni*16+col)
    ushort* dst = Vt + (size_t)(b * NH + h) * HD * S + (size_t)(n0 >> 6) * 2048;
    #pragma unroll
    for (int mi = 0; mi < 2; mi++)
      #pragma unroll
      for (int ni = 0; ni < 4; ni++)
        #pragma unroll
        for (int r = 0; r < 4; r++)
          dst[ni * 512 + (mi * 16 + quad * 4 + r) * 16 + col] =
              f2bf(acc[mi][ni][r] * rn[ni]);
  }
}

// ---------------- MFMA attention: dual 32x32 q-tiles per wave (R5) -----------
// Identical to R5 (best measured: 56.2 us) except the accP epilogue now packs
// partials to bf16 (cvt_pk, RNE): WRITE 33.8 -> 16.9 MB and combine's read
// halves. Dual q-tiles per wave share K/V frags (2x ILP for the
// QK->exp2->cvt->PV chains). ~96 regs at __launch_bounds__(256,4) -- DO NOT
// raise waves/EU (VGPR+AGPR unified file; R2/R4 spilled at (256,8)); R6 showed
// single-tile +TLP loses to dual-tile ILP. KSPLIT=4, grid 1024 = 4 blocks/CU.
// Bijective XCD swizzle. Zero LDS.
__global__ __launch_bounds__(256, 4) void attn_kernel(const ushort* __restrict__ Qn,
                                                      const ushort* __restrict__ Kn,
                                                      const ushort* __restrict__ Vt,
                                                      ushort* __restrict__ accPb,
                                                      float* __restrict__ lP) {
  const int NWG = (S / 256) * NH * KSPLIT * 2;  // 1024
  const int bid = blockIdx.x;
  const int id = (bid & 7) * (NWG / 8) + (bid >> 3);
  const int qt = id & 15;       // 16 q-tiles of 256 rows
  const int grp = id >> 4;      // ((b*KSPLIT + kp) << 3) | h
  const int h = grp & 7;
  const int kp = (grp >> 3) & (KSPLIT - 1);
  const int b = (grp >> 3) / KSPLIT;
  const int wid = threadIdx.x >> 6, lane = threadIdx.x & 63;
  const int ln = lane & 31, hi = lane >> 5;
  const int qA = qt * 256 + wid * 64;   // tile A rows qA..qA+31
  const int qB = qA + 32;               // tile B rows qB..qB+31

  const ushort* Qh = Qn + (size_t)(b * NH + h) * S * HD;

  // Q as B-frag: col=q=ln, ch = half*16 + 8*hi + j
  bf16x8 qfA0 = *(const bf16x8*)&Qh[(size_t)(qA + ln) * HD + hi * 8];
  bf16x8 qfA1 = *(const bf16x8*)&Qh[(size_t)(qA + ln) * HD + 16 + hi * 8];
  bf16x8 qfB0 = *(const bf16x8*)&Qh[(size_t)(qB + ln) * HD + hi * 8];
  bf16x8 qfB1 = *(const bf16x8*)&Qh[(size_t)(qB + ln) * HD + 16 + hi * 8];

  const f32x16 z = {};
  f32x16 accA = {}, accB = {};  // out^T tiles: row=d, col=q
  float laccA = 0.f, laccB = 0.f;

  const int kt0 = kp * (S / KSPLIT);
  // fragment-panel bases; every frag load = base + frag_offset + loff
  const int loff = (ln * 2 + hi) * 8;
  const ushort* Kp = Kn + (size_t)(b * NH + h) * S * HD + (size_t)kt0 * 32 + loff;
  const ushort* Vp = Vt + (size_t)(b * NH + h) * HD * S + (size_t)kt0 * 32 + loff;

  bf16x8 kf0 = *(const bf16x8*)&Kp[0];
  bf16x8 kf1 = *(const bf16x8*)&Kp[512];
  bf16x8 vf0 = *(const bf16x8*)&Vp[0];
  bf16x8 vf1 = *(const bf16x8*)&Vp[512];

  #pragma unroll 1
  for (int it = 0; it < S / KSPLIT / 32; ++it) {   // 32-key steps
    f32x16 sA = __builtin_amdgcn_mfma_f32_32x32x16_bf16(kf0, qfA0, z, 0, 0, 0);
    sA = __builtin_amdgcn_mfma_f32_32x32x16_bf16(kf1, qfA1, sA, 0, 0, 0);
    f32x16 sB = __builtin_amdgcn_mfma_f32_32x32x16_bf16(kf0, qfB0, z, 0, 0, 0);
    sB = __builtin_amdgcn_mfma_f32_32x32x16_bf16(kf1, qfB1, sB, 0, 0, 0);
    Kp += 1024;
    kf0 = *(const bf16x8*)&Kp[0];      // prefetch next tile's K (overread stays in ws)
    kf1 = *(const bf16x8*)&Kp[512];

    bf16x8 pfA0, pfA1;
    s_to_pf(sA, pfA0, pfA1, laccA);
    accA = __builtin_amdgcn_mfma_f32_32x32x16_bf16(vf0, pfA0, accA, 0, 0, 0);
    accA = __builtin_amdgcn_mfma_f32_32x32x16_bf16(vf1, pfA1, accA, 0, 0, 0);

    bf16x8 pfB0, pfB1;
    s_to_pf(sB, pfB0, pfB1, laccB);
    accB = __builtin_amdgcn_mfma_f32_32x32x16_bf16(vf0, pfB0, accB, 0, 0, 0);
    accB = __builtin_amdgcn_mfma_f32_32x32x16_bf16(vf1, pfB1, accB, 0, 0, 0);

    Vp += 1024;
    vf0 = *(const bf16x8*)&Vp[0];      // prefetch next tile's V
    vf1 = *(const bf16x8*)&Vp[512];
  }

  // acc[r]: d = (r&3) + 8*(r>>2) + 4*hi, q = ln; pack f32 pairs -> bf16
  ushort* ap = accPb + ((size_t)((kp * 2 + b) * NH + h)) * S * HD;
  const size_t rowA = (size_t)(qA + ln) * HD;
  const size_t rowB = (size_t)(qB + ln) * HD;
  #pragma unroll
  for (int g = 0; g < 4; g++) {
    uint2 u;
    u.x = cvt_pk_bf16(accA[4 * g + 0], accA[4 * g + 1]);
    u.y = cvt_pk_bf16(accA[4 * g + 2], accA[4 * g + 3]);
    *(uint2*)&ap[rowA + g * 8 + hi * 4] = u;
    uint2 v;
    v.x = cvt_pk_bf16(accB[4 * g + 0], accB[4 * g + 1]);
    v.y = cvt_pk_bf16(accB[4 * g + 2], accB[4 * g + 3]);
    *(uint2*)&ap[rowB + g * 8 + hi * 4] = v;
  }
  const float lsA = laccA + __shfl_xor(laccA, 32, 64);
  const float lsB = laccB + __shfl_xor(laccB, 32, 64);
  if (hi == 0) {
    float* lp = lP + ((size_t)((kp * 2 + b) * NH + h)) * S;
    lp[qA + ln] = lsA;
    lp[qB + ln] = lsB;
  }
}

// ---------------- combine K-split partials (bf16) -> Yt [b][s][256] bf16 -----
__global__ __launch_bounds__(256) void combine_kernel(const ushort* __restrict__ accPb,
                                                      const float* __restrict__ lP,
                                                      ushort* __restrict__ Yt) {
  const int tid = blockIdx.x * 256 + threadIdx.x;
  const int dg = tid & 7;
  const int q = (tid >> 3) & (S - 1);
  const int h = (tid >> 15) & 7;
  const int b = tid >> 18;
  const size_t i0 = ((size_t)(b * NH + h)) * S + q;
  const size_t part = (size_t)2 * NH * S;
  float sx = 0.f, sy = 0.f, sz = 0.f, sw = 0.f, L = 0.f;
  #pragma unroll
  for (int p = 0; p < KSPLIT; p++) {
    const ushort4 a = *(const ushort4*)&accPb[(size_t)p * part * HD + i0 * HD + dg * 4];
    sx += bf2f(a.x); sy += bf2f(a.y); sz += bf2f(a.z); sw += bf2f(a.w);
    L += lP[(size_t)p * part + i0];
  }
  const float rl = 1.0f / L;
  ushort4 o;
  o.x = f2bf(sx * rl);
  o.y = f2bf(sy * rl);
  o.z = f2bf(sz * rl);
  o.w = f2bf(sw * rl);
  *(ushort4*)&Yt[((size_t)b * S + q) * CIN + h * HD + dg * 4] = o;
}

// ---------------- conv2: OUT[b][m][s] fp32 = Wo . Yt, fused mp_add -----------
// Block = 4 waves covering 64m x 64n (wave tile 32x32). Grid (64,4,2) = 512
// blocks = 2 blocks/CU (R5 had 1/CU): 2x latency hiding at IDENTICAL operand
// traffic (Yt still read by exactly 4 m-blocks; R7's 16x re-read regressed).
__global__ __launch_bounds__(256) void conv2_kernel(const ushort* __restrict__ W,
                                                    const ushort* __restrict__ Bm,
                                                    const float* __restrict__ RES,
                                                    float* __restrict__ OUT) {
  const int b = blockIdx.z;
  const int wid = threadIdx.x >> 6, lane = threadIdx.x & 63;
  const int col = lane & 15, quad = lane >> 4;
  const int m0 = blockIdx.y * 64 + (wid >> 1) * 32;
  const int n0 = blockIdx.x * 64 + (wid & 1) * 32;
  const ushort* Bb = Bm + (size_t)b * S * CIN;
  f32x4 acc[2][2] = {};
  #pragma unroll
  for (int k0 = 0; k0 < CIN; k0 += 32) {
    bf16x8 af[2], bf[2];
    #pragma unroll
    for (int mi = 0; mi < 2; mi++)
      af[mi] = *(const bf16x8*)&W[(size_t)(m0 + mi * 16 + col) * CIN + k0 + quad * 8];
    #pragma unroll
    for (int ni = 0; ni < 2; ni++)
      bf[ni] = *(const bf16x8*)&Bb[(size_t)(n0 + ni * 16 + col) * CIN + k0 + quad * 8];
    #pragma unroll
    for (int mi = 0; mi < 2; mi++)
      #pragma unroll
      for (int ni = 0; ni < 2; ni++)
        acc[mi][ni] = __builtin_amdgcn_mfma_f32_16x16x32_bf16(af[mi], bf[ni], acc[mi][ni], 0, 0, 0);
  }
  const float tc = 0.3f, om = 0.7f, inv = 1.3130643285972254f;
  #pragma unroll
  for (int mi = 0; mi < 2; mi++)
    #pragma unroll
    for (int ni = 0; ni < 2; ni++)
      #pragma unroll
      for (int r = 0; r < 4; r++) {
        const size_t idx = ((size_t)(b * CIN + m0 + mi * 16 + quad * 4 + r)) * S + n0 + ni * 16 + col;
        OUT[idx] = (om * RES[idx] + tc * acc[mi][ni][r]) * inv;
      }
}

// ---------------- launch ----------------
extern "C" void kernel_launch(void* const* d_in, const int* in_sizes, int n_in,
                              void* d_out, int out_size, void* d_ws, size_t ws_size,
                              hipStream_t stream) {
  const float* x = (const float*)d_in[0];
  const float* w_qkv = (const float*)d_in[1];
  const float* w_out = (const float*)d_in[2];
  float* out = (float*)d_out;

  ushort* p = (ushort*)d_ws;
  ushort* wqb = p; p += (size_t)C3 * CIN;
  ushort* wob = p; p += (size_t)CIN * CIN;
  ushort* Qn = p; p += (size_t)2 * NH * S * HD;
  ushort* Kn = p; p += (size_t)2 * NH * S * HD;
  ushort* Vt = p; p += (size_t)2 * NH * S * HD;
  ushort* Yt = p; p += (size_t)2 * S * CIN;
  // Region R: Xt (4.2 MB bf16) dies after conv1_fused; accPb bf16
  // (KSPLIT*2*8*4096*32 ushorts = 16.8 MB) aliases the same region.
  ushort* R = p; p += (size_t)KSPLIT * 2 * NH * S * HD;  // 16.8 MB
  ushort* Xt = R;
  ushort* accPb = R;
  float* lP = (float*)p;  // KSPLIT*2*8*4096 floats = 1 MB

  wnorm_kernel<<<(C3 + CIN) / 4, 256, 0, stream>>>(w_qkv, w_out, wqb, wob);
  xt_kernel<<<dim3(S / 64, CIN / 64, 2), 256, 0, stream>>>(x, Xt);
  conv1_fused_kernel<<<dim3(S / 128, C3 / 64, 2), 256, 0, stream>>>(wqb, Xt, Qn, Kn, Vt);
  attn_kernel<<<(S / 256) * NH * KSPLIT * 2, 256, 0, stream>>>(Qn, Kn, Vt, accPb, lP);
  combine_kernel<<<2048, 256, 0, stream>>>(accPb, lP, Yt);
  conv2_kernel<<<dim3(S / 64, CIN / 64, 2), 256, 0, stream>>>(wob, Yt, x, out);
}

// Round 9
// 144.608 us; speedup vs baseline: 1.1259x; 1.0569x over previous
//
#include <hip/hip_runtime.h>
#include <hip/hip_bf16.h>
#include <math.h>

#define S 4096
#define CIN 256
#define C3 768
#define NH 8
#define HD 32
#define KSPLIT 4

static constexpr float EPS = 1e-4f;

typedef __attribute__((ext_vector_type(8))) __bf16 bf16x8;
typedef __attribute__((ext_vector_type(4))) float f32x4;
typedef __attribute__((ext_vector_type(16))) float f32x16;
typedef __attribute__((ext_vector_type(4))) unsigned u32x4;

static inline __device__ ushort f2bf(float f) {  // RN-even
  unsigned u = __float_as_uint(f);
  return (ushort)((u + 0x7fffu + ((u >> 16) & 1u)) >> 16);
}
static inline __device__ float bf2f(ushort u) {
  return __uint_as_float((unsigned)u << 16);
}

// v_cvt_pk_bf16_f32: dst.lo16 = bf16(lo), dst.hi16 = bf16(hi); RNE (no builtin)
static inline __device__ unsigned cvt_pk_bf16(float lo, float hi) {
  unsigned r;
  asm("v_cvt_pk_bf16_f32 %0, %1, %2" : "=v"(r) : "v"(lo), "v"(hi));
  return r;
}
// v_permlane32_swap_b32: a.hi32lanes <-> b.lo32lanes.
static inline __device__ void plane32_swap(unsigned& a, unsigned& b) {
  asm("v_permlane32_swap_b32 %0, %1" : "+v"(a), "+v"(b));
}

#define EXP2 __builtin_amdgcn_exp2f

// All GEMM operands live in [16 rows][32 ch] = 1KB fragment panels:
//   elem (r, c) of tile -> tile_base + (r&15)*32 + (c&31)
//   frag load (16 rows x 8 ch per lane) = tile_base + col*32 + quad*8  (dense 1KB)
// This kills the 64-cache-line-per-load gather that cost attn 40us pre-R3 and
// has been costing conv1/conv2/xt the same ever since.

// Convert one 32x32 QK score tile (D-layout: col=q=lane&31, row=k=(r&3)+8*(r>>2)+4*hi)
// to two PV operand fragments (col/row=q, k = frag*8 elements at 8*hi+j) fully
// in registers: 8 cvt_pk + 4 permlane32_swap. Accumulates the lane's 16 exp
// values into lacc (softmax denominator partial; full denom = lacc + shfl_xor(lacc,32)).
static inline __device__ void s_to_pf(const f32x16 s, bf16x8& plo, bf16x8& phi,
                                      float& lacc) {
  float e0 = EXP2(s[0]), e1 = EXP2(s[1]), e2 = EXP2(s[2]), e3 = EXP2(s[3]);
  float e4 = EXP2(s[4]), e5 = EXP2(s[5]), e6 = EXP2(s[6]), e7 = EXP2(s[7]);
  float e8 = EXP2(s[8]), e9 = EXP2(s[9]), e10 = EXP2(s[10]), e11 = EXP2(s[11]);
  float e12 = EXP2(s[12]), e13 = EXP2(s[13]), e14 = EXP2(s[14]), e15 = EXP2(s[15]);
  lacc += (((e0 + e1) + (e2 + e3)) + ((e4 + e5) + (e6 + e7))) +
          (((e8 + e9) + (e10 + e11)) + ((e12 + e13) + (e14 + e15)));
  unsigned c0 = cvt_pk_bf16(e0, e1);
  unsigned c1 = cvt_pk_bf16(e2, e3);
  unsigned c2 = cvt_pk_bf16(e4, e5);
  unsigned c3 = cvt_pk_bf16(e6, e7);
  plane32_swap(c0, c2);
  plane32_swap(c1, c3);
  u32x4 lo4 = {c0, c1, c2, c3};
  plo = __builtin_bit_cast(bf16x8, lo4);
  unsigned c4 = cvt_pk_bf16(e8, e9);
  unsigned c5 = cvt_pk_bf16(e10, e11);
  unsigned c6 = cvt_pk_bf16(e12, e13);
  unsigned c7 = cvt_pk_bf16(e14, e15);
  plane32_swap(c4, c6);
  plane32_swap(c5, c7);
  u32x4 hi4 = {c4, c5, c6, c7};
  phi = __builtin_bit_cast(bf16x8, hi4);
}

// ---------------- weight norm -> 16x32 fragment panels -----------------------
__global__ __launch_bounds__(256) void wnorm_kernel(const float* __restrict__ w_qkv,
                                                    const float* __restrict__ w_out,
                                                    ushort* __restrict__ wqb,
                                                    ushort* __restrict__ wob) {
  const int row = blockIdx.x * 4 + (threadIdx.x >> 6);
  const int lane = threadIdx.x & 63;
  const bool is_q = row < C3;
  const int r2 = is_q ? row : row - C3;
  const float* wr = (is_q ? w_qkv : w_out) + (size_t)r2 * CIN;
  float v[4];
  #pragma unroll
  for (int i = 0; i < 4; i++) v[i] = wr[lane + 64 * i];
  float ss = v[0] * v[0] + v[1] * v[1] + v[2] * v[2] + v[3] * v[3];
  #pragma unroll
  for (int off = 32; off > 0; off >>= 1) ss += __shfl_down(ss, off, 64);
  ss = __shfl(ss, 0, 64);
  const float scale = 1.0f / (sqrtf(ss) + 16.0f * EPS);
  ushort* whr = (is_q ? wqb : wob);
  #pragma unroll
  for (int i = 0; i < 4; i++) {
    const int c = lane + 64 * i;
    whr[((size_t)(r2 >> 4) * (CIN / 32) + (c >> 5)) * 512 + (r2 & 15) * 32 + (c & 31)] =
        f2bf(v[i] * scale);
  }
}

// ---------------- X [b][c][s] fp32 -> Xt 16x32 panels ------------------------
__global__ __launch_bounds__(256) void xt_kernel(const float* __restrict__ X,
                                                 ushort* __restrict__ Xt) {
  const int b = blockIdx.z;
  const int s0 = blockIdx.x * 64, c0 = blockIdx.y * 64;
  __shared__ ushort T[64][72];
  const int tc = threadIdx.x >> 4;
  const int ts = threadIdx.x & 15;
  #pragma unroll
  for (int i = 0; i < 4; i++) {
    const float4 v = *(const float4*)&X[((size_t)(b * CIN + c0 + tc + 16 * i)) * S + s0 + ts * 4];
    ushort4 u;
    u.x = f2bf(v.x); u.y = f2bf(v.y); u.z = f2bf(v.z); u.w = f2bf(v.w);
    *(ushort4*)&T[tc + 16 * i][ts * 4] = u;
  }
  __syncthreads();
  #pragma unroll
  for (int i = 0; i < 4; i++) {
    const int sr = tc + 16 * i;
    const int s = s0 + sr;
    const int c = c0 + ts * 4;
    ushort4 u;
    u.x = T[ts * 4 + 0][sr];
    u.y = T[ts * 4 + 1][sr];
    u.z = T[ts * 4 + 2][sr];
    u.w = T[ts * 4 + 3][sr];
    *(ushort4*)&Xt[(((size_t)b * (S / 16) + (s >> 4)) * (CIN / 32) + (c >> 5)) * 512 +
                   (s & 15) * 32 + (c & 31)] = u;
  }
}

// ---------------- conv1 fused with pixel-norm + layout fan-out ---------------
// A (W) and B (Xt) both read from 16x32 panels: every frag load is dense 1KB.
// Outputs: Q rows [bh][q][HD]; K/V in attn fragment panels (R3 layout).
__global__ __launch_bounds__(256) void conv1_fused_kernel(const ushort* __restrict__ W,
                                                          const ushort* __restrict__ Bm,
                                                          ushort* __restrict__ Qn,
                                                          ushort* __restrict__ Kn,
                                                          ushort* __restrict__ Vt) {
  const int b = blockIdx.z;
  const int wid = threadIdx.x >> 6, lane = threadIdx.x & 63;
  const int col = lane & 15, quad = lane >> 4;
  const int m0 = blockIdx.y * 64 + (wid >> 1) * 32;  // 32-aligned: one head group
  const int n0 = blockIdx.x * 128 + (wid & 1) * 64;
  const ushort* Bb = Bm + (size_t)b * (S / 16) * (CIN / 32) * 512;
  const int lofs = col * 32 + quad * 8;
  f32x4 acc[2][4] = {};
  #pragma unroll
  for (int k0 = 0; k0 < CIN; k0 += 32) {
    bf16x8 af[2], bf[4];
    #pragma unroll
    for (int mi = 0; mi < 2; mi++)
      af[mi] = *(const bf16x8*)&W[((size_t)(m0 / 16 + mi) * (CIN / 32) + (k0 >> 5)) * 512 + lofs];
    #pragma unroll
    for (int ni = 0; ni < 4; ni++)
      bf[ni] = *(const bf16x8*)&Bb[((size_t)(n0 / 16 + ni) * (CIN / 32) + (k0 >> 5)) * 512 + lofs];
    #pragma unroll
    for (int mi = 0; mi < 2; mi++)
      #pragma unroll
      for (int ni = 0; ni < 4; ni++)
        acc[mi][ni] = __builtin_amdgcn_mfma_f32_16x16x32_bf16(af[mi], bf[ni], acc[mi][ni], 0, 0, 0);
  }

  const int g = m0 >> 5;   // 0..23: group; 0-7 Q, 8-15 K, 16-23 V
  const int h = g & 7;
  float rn[4];
  #pragma unroll
  for (int ni = 0; ni < 4; ni++) {
    float ss = 0.f;
    #pragma unroll
    for (int mi = 0; mi < 2; mi++)
      #pragma unroll
      for (int r = 0; r < 4; r++) ss += acc[mi][ni][r] * acc[mi][ni][r];
    ss += __shfl_xor(ss, 16, 64);
    ss += __shfl_xor(ss, 32, 64);
    rn[ni] = rsqrtf(ss * (1.0f / HD) + EPS);
    if (g < 8) rn[ni] *= 0.2550348190698169f;  // log2(e)/sqrt(32) folded into Q
  }

  if (g < 8) {  // Q: row layout [q][HD]
    ushort* dst = Qn + (size_t)(b * NH + h) * S * HD;
    #pragma unroll
    for (int mi = 0; mi < 2; mi++)
      #pragma unroll
      for (int ni = 0; ni < 4; ni++) {
        ushort4 u;
        u.x = f2bf(acc[mi][ni][0] * rn[ni]);
        u.y = f2bf(acc[mi][ni][1] * rn[ni]);
        u.z = f2bf(acc[mi][ni][2] * rn[ni]);
        u.w = f2bf(acc[mi][ni][3] * rn[ni]);
        *(ushort4*)&dst[(size_t)(n0 + ni * 16 + col) * HD + mi * 16 + quad * 4] = u;
      }
  } else if (g < 16) {  // K: attn fragment panels
    ushort* dst = Kn + (size_t)(b * NH + h) * S * HD + (size_t)(n0 >> 5) * 1024;
    #pragma unroll
    for (int mi = 0; mi < 2; mi++)
      #pragma unroll
      for (int ni = 0; ni < 4; ni++) {
        ushort4 u;
        u.x = f2bf(acc[mi][ni][0] * rn[ni]);
        u.y = f2bf(acc[mi][ni][1] * rn[ni]);
        u.z = f2bf(acc[mi][ni][2] * rn[ni]);
        u.w = f2bf(acc[mi][ni][3] * rn[ni]);
        *(ushort4*)&dst[(ni >> 1) * 1024 + mi * 512 + ((ni & 1) * 16 + col) * 16 +
                        (quad >> 1) * 8 + (quad & 1) * 4] = u;
      }
  } else {  // V: attn fragment panels (d = mi*16+quad*4+r, key = n0+ni*16+col)
    ushort* dst = Vt + (size_t)(b * NH + h) * HD * S + (size_t)(n0 >> 6) * 2048;
    #pragma unroll
    for (int mi = 0; mi < 2; mi++)
      #pragma unroll
      for (int ni = 0; ni < 4; ni++)
        #pragma unroll
        for (int r = 0; r < 4; r++)
          dst[ni * 512 + (mi * 16 + quad * 4 + r) * 16 + col] =
              f2bf(acc[mi][ni][r] * rn[ni]);
  }
}

// ---------------- MFMA attention: dual 32x32 q-tiles per wave (R8) -----------
// Unchanged from R8 (56.0 us measured): dual q-tiles share K/V frags (2x ILP),
// bf16 partial output (cvt_pk). ~96 regs at __launch_bounds__(256,4) -- DO NOT
// raise waves/EU (VGPR+AGPR unified file; R2/R4 spilled at (256,8)); R6 showed
// single-tile +TLP loses to dual-tile ILP. KSPLIT=4, grid 1024 = 4 blocks/CU.
// Bijective XCD swizzle. Zero LDS.
__global__ __launch_bounds__(256, 4) void attn_kernel(const ushort* __restrict__ Qn,
                                                      const ushort* __restrict__ Kn,
                                                      const ushort* __restrict__ Vt,
                                                      ushort* __restrict__ accPb,
                                                      float* __restrict__ lP) {
  const int NWG = (S / 256) * NH * KSPLIT * 2;  // 1024
  const int bid = blockIdx.x;
  const int id = (bid & 7) * (NWG / 8) + (bid >> 3);
  const int qt = id & 15;       // 16 q-tiles of 256 rows
  const int grp = id >> 4;      // ((b*KSPLIT + kp) << 3) | h
  const int h = grp & 7;
  const int kp = (grp >> 3) & (KSPLIT - 1);
  const int b = (grp >> 3) / KSPLIT;
  const int wid = threadIdx.x >> 6, lane = threadIdx.x & 63;
  const int ln = lane & 31, hi = lane >> 5;
  const int qA = qt * 256 + wid * 64;   // tile A rows qA..qA+31
  const int qB = qA + 32;               // tile B rows qB..qB+31

  const ushort* Qh = Qn + (size_t)(b * NH + h) * S * HD;

  // Q as B-frag: col=q=ln, ch = half*16 + 8*hi + j
  bf16x8 qfA0 = *(const bf16x8*)&Qh[(size_t)(qA + ln) * HD + hi * 8];
  bf16x8 qfA1 = *(const bf16x8*)&Qh[(size_t)(qA + ln) * HD + 16 + hi * 8];
  bf16x8 qfB0 = *(const bf16x8*)&Qh[(size_t)(qB + ln) * HD + hi * 8];
  bf16x8 qfB1 = *(const bf16x8*)&Qh[(size_t)(qB + ln) * HD + 16 + hi * 8];

  const f32x16 z = {};
  f32x16 accA = {}, accB = {};  // out^T tiles: row=d, col=q
  float laccA = 0.f, laccB = 0.f;

  const int kt0 = kp * (S / KSPLIT);
  // fragment-panel bases; every frag load = base + frag_offset + loff
  const int loff = (ln * 2 + hi) * 8;
  const ushort* Kp = Kn + (size_t)(b * NH + h) * S * HD + (size_t)kt0 * 32 + loff;
  const ushort* Vp = Vt + (size_t)(b * NH + h) * HD * S + (size_t)kt0 * 32 + loff;

  bf16x8 kf0 = *(const bf16x8*)&Kp[0];
  bf16x8 kf1 = *(const bf16x8*)&Kp[512];
  bf16x8 vf0 = *(const bf16x8*)&Vp[0];
  bf16x8 vf1 = *(const bf16x8*)&Vp[512];

  #pragma unroll 1
  for (int it = 0; it < S / KSPLIT / 32; ++it) {   // 32-key steps
    f32x16 sA = __builtin_amdgcn_mfma_f32_32x32x16_bf16(kf0, qfA0, z, 0, 0, 0);
    sA = __builtin_amdgcn_mfma_f32_32x32x16_bf16(kf1, qfA1, sA, 0, 0, 0);
    f32x16 sB = __builtin_amdgcn_mfma_f32_32x32x16_bf16(kf0, qfB0, z, 0, 0, 0);
    sB = __builtin_amdgcn_mfma_f32_32x32x16_bf16(kf1, qfB1, sB, 0, 0, 0);
    Kp += 1024;
    kf0 = *(const bf16x8*)&Kp[0];      // prefetch next tile's K (overread stays in ws)
    kf1 = *(const bf16x8*)&Kp[512];

    bf16x8 pfA0, pfA1;
    s_to_pf(sA, pfA0, pfA1, laccA);
    accA = __builtin_amdgcn_mfma_f32_32x32x16_bf16(vf0, pfA0, accA, 0, 0, 0);
    accA = __builtin_amdgcn_mfma_f32_32x32x16_bf16(vf1, pfA1, accA, 0, 0, 0);

    bf16x8 pfB0, pfB1;
    s_to_pf(sB, pfB0, pfB1, laccB);
    accB = __builtin_amdgcn_mfma_f32_32x32x16_bf16(vf0, pfB0, accB, 0, 0, 0);
    accB = __builtin_amdgcn_mfma_f32_32x32x16_bf16(vf1, pfB1, accB, 0, 0, 0);

    Vp += 1024;
    vf0 = *(const bf16x8*)&Vp[0];      // prefetch next tile's V
    vf1 = *(const bf16x8*)&Vp[512];
  }

  // acc[r]: d = (r&3) + 8*(r>>2) + 4*hi, q = ln; pack f32 pairs -> bf16
  ushort* ap = accPb + ((size_t)((kp * 2 + b) * NH + h)) * S * HD;
  const size_t rowA = (size_t)(qA + ln) * HD;
  const size_t rowB = (size_t)(qB + ln) * HD;
  #pragma unroll
  for (int g = 0; g < 4; g++) {
    uint2 u;
    u.x = cvt_pk_bf16(accA[4 * g + 0], accA[4 * g + 1]);
    u.y = cvt_pk_bf16(accA[4 * g + 2], accA[4 * g + 3]);
    *(uint2*)&ap[rowA + g * 8 + hi * 4] = u;
    uint2 v;
    v.x = cvt_pk_bf16(accB[4 * g + 0], accB[4 * g + 1]);
    v.y = cvt_pk_bf16(accB[4 * g + 2], accB[4 * g + 3]);
    *(uint2*)&ap[rowB + g * 8 + hi * 4] = v;
  }
  const float lsA = laccA + __shfl_xor(laccA, 32, 64);
  const float lsB = laccB + __shfl_xor(laccB, 32, 64);
  if (hi == 0) {
    float* lp = lP + ((size_t)((kp * 2 + b) * NH + h)) * S;
    lp[qA + ln] = lsA;
    lp[qB + ln] = lsB;
  }
}

// ---------------- combine K-split partials (bf16) -> Yt 16x32 panels ---------
__global__ __launch_bounds__(256) void combine_kernel(const ushort* __restrict__ accPb,
                                                      const float* __restrict__ lP,
                                                      ushort* __restrict__ Yt) {
  const int tid = blockIdx.x * 256 + threadIdx.x;
  const int dg = tid & 7;
  const int q = (tid >> 3) & (S - 1);
  const int h = (tid >> 15) & 7;
  const int b = tid >> 18;
  const size_t i0 = ((size_t)(b * NH + h)) * S + q;
  const size_t part = (size_t)2 * NH * S;
  float sx = 0.f, sy = 0.f, sz = 0.f, sw = 0.f, L = 0.f;
  #pragma unroll
  for (int p = 0; p < KSPLIT; p++) {
    const ushort4 a = *(const ushort4*)&accPb[(size_t)p * part * HD + i0 * HD + dg * 4];
    sx += bf2f(a.x); sy += bf2f(a.y); sz += bf2f(a.z); sw += bf2f(a.w);
    L += lP[(size_t)p * part + i0];
  }
  const float rl = 1.0f / L;
  ushort4 o;
  o.x = f2bf(sx * rl);
  o.y = f2bf(sy * rl);
  o.z = f2bf(sz * rl);
  o.w = f2bf(sw * rl);
  // Yt panel: row=q, ch tile = h (c = h*32 + dg*4)
  *(ushort4*)&Yt[(((size_t)b * (S / 16) + (q >> 4)) * (CIN / 32) + h) * 512 +
                 (q & 15) * 32 + dg * 4] = o;
}

// ---------------- conv2: OUT[b][m][s] fp32 = Wo . Yt, fused mp_add -----------
// A (Wo) and B (Yt) from 16x32 panels (dense frag loads). Block = 4 waves
// covering 64m x 64n. Grid (64,4,2) = 512 blocks = 2 blocks/CU (R8 config).
__global__ __launch_bounds__(256) void conv2_kernel(const ushort* __restrict__ W,
                                                    const ushort* __restrict__ Bm,
                                                    const float* __restrict__ RES,
                                                    float* __restrict__ OUT) {
  const int b = blockIdx.z;
  const int wid = threadIdx.x >> 6, lane = threadIdx.x & 63;
  const int col = lane & 15, quad = lane >> 4;
  const int m0 = blockIdx.y * 64 + (wid >> 1) * 32;
  const int n0 = blockIdx.x * 64 + (wid & 1) * 32;
  const ushort* Bb = Bm + (size_t)b * (S / 16) * (CIN / 32) * 512;
  const int lofs = col * 32 + quad * 8;
  f32x4 acc[2][2] = {};
  #pragma unroll
  for (int k0 = 0; k0 < CIN; k0 += 32) {
    bf16x8 af[2], bf[2];
    #pragma unroll
    for (int mi = 0; mi < 2; mi++)
      af[mi] = *(const bf16x8*)&W[((size_t)(m0 / 16 + mi) * (CIN / 32) + (k0 >> 5)) * 512 + lofs];
    #pragma unroll
    for (int ni = 0; ni < 2; ni++)
      bf[ni] = *(const bf16x8*)&Bb[((size_t)(n0 / 16 + ni) * (CIN / 32) + (k0 >> 5)) * 512 + lofs];
    #pragma unroll
    for (int mi = 0; mi < 2; mi++)
      #pragma unroll
      for (int ni = 0; ni < 2; ni++)
        acc[mi][ni] = __builtin_amdgcn_mfma_f32_16x16x32_bf16(af[mi], bf[ni], acc[mi][ni], 0, 0, 0);
  }
  const float tc = 0.3f, om = 0.7f, inv = 1.3130643285972254f;
  #pragma unroll
  for (int mi = 0; mi < 2; mi++)
    #pragma unroll
    for (int ni = 0; ni < 2; ni++)
      #pragma unroll
      for (int r = 0; r < 4; r++) {
        const size_t idx = ((size_t)(b * CIN + m0 + mi * 16 + quad * 4 + r)) * S + n0 + ni * 16 + col;
        OUT[idx] = (om * RES[idx] + tc * acc[mi][ni][r]) * inv;
      }
}

// ---------------- launch ----------------
extern "C" void kernel_launch(void* const* d_in, const int* in_sizes, int n_in,
                              void* d_out, int out_size, void* d_ws, size_t ws_size,
                              hipStream_t stream) {
  const float* x = (const float*)d_in[0];
  const float* w_qkv = (const float*)d_in[1];
  const float* w_out = (const float*)d_in[2];
  float* out = (float*)d_out;

  ushort* p = (ushort*)d_ws;
  ushort* wqb = p; p += (size_t)C3 * CIN;
  ushort* wob = p; p += (size_t)CIN * CIN;
  ushort* Qn = p; p += (size_t)2 * NH * S * HD;
  ushort* Kn = p; p += (size_t)2 * NH * S * HD;
  ushort* Vt = p; p += (size_t)2 * NH * S * HD;
  ushort* Yt = p; p += (size_t)2 * S * CIN;
  // Region R: Xt (4.2 MB bf16) dies after conv1_fused; accPb bf16
  // (KSPLIT*2*8*4096*32 ushorts = 16.8 MB) aliases the same region.
  ushort* R = p; p += (size_t)KSPLIT * 2 * NH * S * HD;  // 16.8 MB
  ushort* Xt = R;
  ushort* accPb = R;
  float* lP = (float*)p;  // KSPLIT*2*8*4096 floats = 1 MB

  wnorm_kernel<<<(C3 + CIN) / 4, 256, 0, stream>>>(w_qkv, w_out, wqb, wob);
  xt_kernel<<<dim3(S / 64, CIN / 64, 2), 256, 0, stream>>>(x, Xt);
  conv1_fused_kernel<<<dim3(S / 128, C3 / 64, 2), 256, 0, stream>>>(wqb, Xt, Qn, Kn, Vt);
  attn_kernel<<<(S / 256) * NH * KSPLIT * 2, 256, 0, stream>>>(Qn, Kn, Vt, accPb, lP);
  combine_kernel<<<2048, 256, 0, stream>>>(accPb, lP, Yt);
  conv2_kernel<<<dim3(S / 64, CIN / 64, 2), 256, 0, stream>>>(wob, Yt, x, out);
}